// Round 2
// baseline (287.469 us; speedup 1.0000x reference)
//
#include <hip/hip_runtime.h>

#define TT 4096
#define BLK 256
#define PER 16   // TT / BLK
#define EPSV 1e-8f

// XOR swizzle on a float index: spreads the 64B-stride per-thread groups
// across banks while preserving 16B (float4) contiguity and alignment.
// (i>>5)&7 is constant within any aligned 4-float group, so swizzled
// float4 accesses stay contiguous and 16B-aligned.
__device__ __forceinline__ int swz(int i) {
  return i ^ (((i >> 5) & 7) << 2);
}

__global__ __launch_bounds__(BLK, 8) void w2_loss_kernel(
    const float* __restrict__ traces,
    const float* __restrict__ q_raw,
    float* __restrict__ part) {
  // lds_buf: phase 1 holds the per-element cdf numerators (lc, swizzled);
  //          phase 2 overwrites each slot in place with d*d (same thread,
  //          same slot -> no extra hazard).
  __shared__ float lds_buf[TT];
  __shared__ float lds_wexcl[BLK];   // per-thread wave-exclusive prefix (v - tot)
  __shared__ float wave_sums[4];
  __shared__ float wave_red[4];

  const int tid = threadIdx.x;
  const long trace = blockIdx.x;
  const float* __restrict__ tr = traces + trace * (long)TT;
  const float* __restrict__ qr = q_raw + trace * (long)TT;

  const int base = tid * PER;

  // ---- trace loads (feed the scan critical path). q_raw is NOT staged:
  // phase 2 gathers it from global with near-sequential wave addresses. ----
  float4 trv[4];
  {
    const float4* tr4 = (const float4*)(tr + base);
#pragma unroll
    for (int j = 0; j < 4; ++j) trv[j] = tr4[j];
  }
  float nb = (base + PER < TT) ? tr[base + PER] : 0.0f;

  // s[i] = traces[i]^2 + eps for own 16 elements + right neighbor.
  float s[PER + 1];
#pragma unroll
  for (int j = 0; j < 4; ++j) {
    s[4 * j + 0] = trv[j].x * trv[j].x + EPSV;
    s[4 * j + 1] = trv[j].y * trv[j].y + EPSV;
    s[4 * j + 2] = trv[j].z * trv[j].z + EPSV;
    s[4 * j + 3] = trv[j].w * trv[j].w + EPSV;
  }
  s[PER] = (base + PER < TT) ? (nb * nb + EPSV) : 0.0f;

  // t[i] = (float)i * 1e-3f  — bit-exact vs arange(T)*1e-3 in fp32.
  float lc[PER + 1];
  lc[0] = 0.0f;
#pragma unroll
  for (int m = 0; m < PER; ++m) {
    float t0 = (float)(base + m) * 1e-3f;
    float t1 = (float)(base + m + 1) * 1e-3f;
    float incr = (base + m < TT - 1) ? 0.5f * (s[m] + s[m + 1]) * (t1 - t0)
                                     : 0.0f;
    lc[m + 1] = lc[m] + incr;
  }
  const float tot = lc[PER];

  // Wave-level inclusive scan of thread totals (wave = 64 lanes).
  float v = tot;
#pragma unroll
  for (int off = 1; off < 64; off <<= 1) {
    float n = __shfl_up(v, off, 64);
    if ((tid & 63) >= off) v += n;
  }
  if ((tid & 63) == 63) wave_sums[tid >> 6] = v;

  // Per-thread wave-exclusive prefix, readable by any thread in phase 2.
  lds_wexcl[tid] = v - tot;

  // Store cdf numerators (lc) into LDS, swizzled, as 4 float4 writes.
  // XOR constant is uniform across this thread's 16-float span.
  const int swb = ((tid >> 1) & 7) << 2;
#pragma unroll
  for (int j = 0; j < 4; ++j) {
    *(float4*)&lds_buf[(base + 4 * j) ^ swb] =
        make_float4(lc[4 * j + 0], lc[4 * j + 1], lc[4 * j + 2], lc[4 * j + 3]);
  }
  __syncthreads();  // covers wave_sums, lds_wexcl, lds_buf

  const float ws0 = wave_sums[0], ws1 = wave_sums[1];
  const float ws2 = wave_sums[2], ws3 = wave_sums[3];
  const float norm = ws0 + ws1 + ws2 + ws3;     // same association as before
  const float inv_norm = 1.0f / norm;

  // Owner-wave offsets, same add order as the original wave_off build.
  // Owner wave of element e = m*256+tid is exactly m>>2 (compile-time).
  const float woff1 = ws0;
  const float woff2 = ws0 + ws1;
  const float woff3 = (ws0 + ws1) + ws2;

  // ---- Phase 2, STRIDED: thread handles e = m*256 + tid. ----
  // LDS reads/writes are lane-consecutive -> conflict-free.
  // q gather addresses are monotone, ~64-wide per wave -> L1/L2 friendly.
  // Every arithmetic expression matches the original bit-for-bit.
#pragma unroll
  for (int g = 0; g < 4; ++g) {
    const float woff = (g == 0) ? 0.0f : ((g == 1) ? woff1 : ((g == 2) ? woff2 : woff3));
#pragma unroll
    for (int mm = 0; mm < 4; ++mm) {
      const int m = 4 * g + mm;
      const int e = (m << 8) + tid;
      const int a = swz(e);
      const float lcv = lds_buf[a];
      const float wex = lds_wexcl[e >> 4];     // broadcast read (16 lanes/addr)
      const float excl = wex + woff;           // == (v - tot) + wave_off
      const float x = (excl + lcv) * inv_norm; // cdf in [0,1]
      float u = x * (float)(TT - 1);           // analytic index on uniform p
      int i0 = (int)floorf(u);
      i0 = (i0 < 0) ? 0 : ((i0 > TT - 2) ? TT - 2 : i0);
      float f = u - (float)i0;
      f = fminf(fmaxf(f, 0.0f), 1.0f);         // jnp.interp endpoint clamp
      const float q0 = qr[i0];
      const float q1 = qr[i0 + 1];
      const float transport = q0 + f * (q1 - q0);
      const float tm = (float)e * 1e-3f;
      const float d = tm - transport;
      lds_buf[a] = d * d;                      // in-place, same thread/slot
    }
  }
  __syncthreads();

  // ---- Phase 3: owner thread reads back its 16 contiguous d^2 values and
  // accumulates in the ORIGINAL order: local += ((d*d) * s[m]) * w. ----
  float dd[PER];
#pragma unroll
  for (int j = 0; j < 4; ++j) {
    const float4 dq = *(const float4*)&lds_buf[(base + 4 * j) ^ swb];
    dd[4 * j + 0] = dq.x;
    dd[4 * j + 1] = dq.y;
    dd[4 * j + 2] = dq.z;
    dd[4 * j + 3] = dq.w;
  }

  float local = 0.0f;
#pragma unroll
  for (int m = 0; m < PER; ++m) {
    float tlo = (float)((base + m == 0) ? 0 : (base + m - 1)) * 1e-3f;
    float thi = (float)((base + m == TT - 1) ? (TT - 1) : (base + m + 1)) * 1e-3f;
    float w = 0.5f * (thi - tlo);              // collapsed trapz weight
    local += dd[m] * s[m] * w;                 // ((d*d)*s[m])*w, as before
  }
  local *= inv_norm;

  // Block reduce, then ONE COALESCED STORE per block (no same-address atomic).
#pragma unroll
  for (int off = 32; off > 0; off >>= 1) local += __shfl_down(local, off, 64);
  if ((tid & 63) == 0) wave_red[tid >> 6] = local;
  __syncthreads();
  if (tid == 0) {
    part[blockIdx.x] = wave_red[0] + wave_red[1] + wave_red[2] + wave_red[3];
  }
}

__global__ __launch_bounds__(BLK) void reduce_kernel(
    const float* __restrict__ part, float* __restrict__ out, int n) {
  __shared__ float wave_red[4];
  const int tid = threadIdx.x;
  float local = 0.0f;
  for (int i = tid; i < n; i += BLK) local += part[i];
#pragma unroll
  for (int off = 32; off > 0; off >>= 1) local += __shfl_down(local, off, 64);
  if ((tid & 63) == 0) wave_red[tid >> 6] = local;
  __syncthreads();
  if (tid == 0) out[0] = wave_red[0] + wave_red[1] + wave_red[2] + wave_red[3];
}

extern "C" void kernel_launch(void* const* d_in, const int* in_sizes, int n_in,
                              void* d_out, int out_size, void* d_ws, size_t ws_size,
                              hipStream_t stream) {
  const float* traces = (const float*)d_in[0];
  const float* q_raw  = (const float*)d_in[3];
  float* out = (float*)d_out;
  float* part = (float*)d_ws;  // 8192 floats = 32 KB scratch

  const int n_traces = in_sizes[0] / TT;  // B*R = 8192
  w2_loss_kernel<<<n_traces, BLK, 0, stream>>>(traces, q_raw, part);
  reduce_kernel<<<1, BLK, 0, stream>>>(part, out, n_traces);
}